// Round 12
// baseline (169.918 us; speedup 1.0000x reference)
//
#include <hip/hip_runtime.h>
#include <math.h>

#define D_MODEL 512
#define NH      8
#define DK      128
#define HALFD   64
#define NKEYS   256
#define TOPK    8
#define NTOK    2048

typedef float f4v __attribute__((ext_vector_type(4)));
static __device__ __forceinline__ float4 ntload(const float4* p) {
  f4v v = __builtin_nontemporal_load(reinterpret_cast<const f4v*>(p));
  return make_float4(v[0], v[1], v[2], v[3]);
}

// ---------------- Kernel A: q = x @ Wq + bq  (fp32 tiled GEMM, round-8 form) ----------------
// M=2048, N=1024, K=512. BM=BN=64, BK=16, 256 threads, 4x4/thread, 512 blocks = 2/CU.
__global__ __launch_bounds__(256) void qproj_gemm(const float* __restrict__ A,
                                                  const float* __restrict__ B,
                                                  const float* __restrict__ bias,
                                                  float* __restrict__ C) {
  const int N = NH * DK, K = D_MODEL;
  __shared__ float As[16][68];
  __shared__ float Bs[16][68];
  int tid = threadIdx.x;
  int tx = tid & 15, ty = tid >> 4;
  int m0 = blockIdx.y * 64, n0 = blockIdx.x * 64;
  int arow = tid >> 2, akk = (tid & 3) << 2;
  int bkr = tid >> 4, bnn = (tid & 15) << 2;
  const float* Aptr = A + (size_t)(m0 + arow) * K + akk;
  const float* Bptr = B + (size_t)bkr * N + n0 + bnn;

  float4 aReg = *(const float4*)Aptr;
  float4 bReg = *(const float4*)Bptr;

  float c[4][4];
#pragma unroll
  for (int i = 0; i < 4; ++i)
#pragma unroll
    for (int j = 0; j < 4; ++j) c[i][j] = 0.f;

  for (int k0 = 0; k0 < K; k0 += 16) {
    As[akk + 0][arow] = aReg.x;
    As[akk + 1][arow] = aReg.y;
    As[akk + 2][arow] = aReg.z;
    As[akk + 3][arow] = aReg.w;
    *(float4*)&Bs[bkr][bnn] = bReg;
    __syncthreads();
    if (k0 + 16 < K) {
      aReg = *(const float4*)(Aptr + k0 + 16);
      bReg = *(const float4*)(Bptr + (size_t)(k0 + 16) * N);
    }
#pragma unroll
    for (int k = 0; k < 16; ++k) {
      float4 a = *(const float4*)&As[k][ty << 2];
      float4 b = *(const float4*)&Bs[k][tx << 2];
      float av[4] = {a.x, a.y, a.z, a.w};
      float bv[4] = {b.x, b.y, b.z, b.w};
#pragma unroll
      for (int i = 0; i < 4; ++i)
#pragma unroll
        for (int j = 0; j < 4; ++j) c[i][j] += av[i] * bv[j];
    }
    __syncthreads();
  }
#pragma unroll
  for (int i = 0; i < 4; ++i) {
    int m = m0 + (ty << 2) + i;
#pragma unroll
    for (int j = 0; j < 4; ++j) {
      int n = n0 + (tx << 2) + j;
      C[(size_t)m * N + n] = c[i][j] + bias[n];
    }
  }
}

// ---------------- Kernel A2: scores = q_half @ keys^T ----------------
__global__ __launch_bounds__(256) void score_gemm(const float* __restrict__ qbuf,
                                                  const float* __restrict__ keys,
                                                  float* __restrict__ scores) {
  __shared__ float As[16][68];
  __shared__ float Bs[16][68];
  int tid = threadIdx.x;
  int tx = tid & 15, ty = tid >> 4;
  int n0 = blockIdx.x * 64, m0 = blockIdx.y * 64, slab = blockIdx.z;
  const float* Ap = qbuf + (size_t)slab * HALFD;
  const float* Bp = keys + (size_t)slab * NKEYS * HALFD;
  float c[4][4];
#pragma unroll
  for (int i = 0; i < 4; ++i)
#pragma unroll
    for (int j = 0; j < 4; ++j) c[i][j] = 0.f;

  for (int k0 = 0; k0 < HALFD; k0 += 16) {
    int row = tid >> 2, kk = (tid & 3) << 2;
    {
      float4 av = *(const float4*)(Ap + (size_t)(m0 + row) * (NH * DK) + k0 + kk);
      As[kk + 0][row] = av.x;
      As[kk + 1][row] = av.y;
      As[kk + 2][row] = av.z;
      As[kk + 3][row] = av.w;
    }
    {
      float4 bv = *(const float4*)(Bp + (size_t)(n0 + row) * HALFD + k0 + kk);
      Bs[kk + 0][row] = bv.x;
      Bs[kk + 1][row] = bv.y;
      Bs[kk + 2][row] = bv.z;
      Bs[kk + 3][row] = bv.w;
    }
    __syncthreads();
#pragma unroll
    for (int k = 0; k < 16; ++k) {
      float4 a = *(const float4*)&As[k][ty << 2];
      float4 b = *(const float4*)&Bs[k][tx << 2];
      float av[4] = {a.x, a.y, a.z, a.w};
      float bv[4] = {b.x, b.y, b.z, b.w};
#pragma unroll
      for (int i = 0; i < 4; ++i)
#pragma unroll
        for (int j = 0; j < 4; ++j) c[i][j] += av[i] * bv[j];
    }
    __syncthreads();
  }
#pragma unroll
  for (int i = 0; i < 4; ++i) {
    int m = m0 + (ty << 2) + i;
    float4 cv = make_float4(c[i][0], c[i][1], c[i][2], c[i][3]);
    *(float4*)&scores[((size_t)m * 16 + slab) * NKEYS + n0 + (tx << 2)] = cv;
  }
}

// ---------------- Kernel B: two-stage top-k + softmax ----------------
#define CE(a, b)                                                        \
  do {                                                                  \
    if (lv[a] < lv[b] || (lv[a] == lv[b] && li[a] > li[b])) {           \
      float tv_ = lv[a]; lv[a] = lv[b]; lv[b] = tv_;                    \
      int ti_ = li[a]; li[a] = li[b]; li[b] = ti_;                      \
    }                                                                   \
  } while (0)

__global__ __launch_bounds__(256) void topk_kernel(const float* __restrict__ scores,
                                                   int* __restrict__ widx,
                                                   float* __restrict__ wval) {
  int tid = threadIdx.x;
  int task = blockIdx.x * 4 + (tid >> 6);
  int ln = tid & 63;
  int b = task >> 3, h = task & 7;
  int s = ln >> 5, l = ln & 31;

  const float* sp = scores + ((size_t)b * 16 + h * 2 + s) * NKEYS + l * 8;
  float lv[8];
  int li[8];
  {
    float4 v0 = *(const float4*)sp;
    float4 v1 = *(const float4*)(sp + 4);
    lv[0] = v0.x; lv[1] = v0.y; lv[2] = v0.z; lv[3] = v0.w;
    lv[4] = v1.x; lv[5] = v1.y; lv[6] = v1.z; lv[7] = v1.w;
#pragma unroll
    for (int m = 0; m < 8; ++m) li[m] = l * 8 + m;
  }
  CE(0, 1); CE(2, 3); CE(0, 2); CE(1, 3); CE(1, 2);
  CE(4, 5); CE(6, 7); CE(4, 6); CE(5, 7); CE(5, 6);
  CE(0, 4); CE(1, 5); CE(2, 6); CE(3, 7);
  CE(2, 4); CE(3, 5);
  CE(1, 2); CE(3, 4); CE(5, 6);

  float wv_cap = 0.f;
  int wn_cap = 0;
#pragma unroll
  for (int k = 0; k < 8; ++k) {
    float v = lv[0];
    int n = li[0];
#pragma unroll
    for (int off = 16; off; off >>= 1) {
      float ov = __shfl_xor(v, off);
      int on = __shfl_xor(n, off);
      if (ov > v || (ov == v && on < n)) { v = ov; n = on; }
    }
    if (l == k) { wv_cap = v; wn_cap = n; }
    if (li[0] == n) {
#pragma unroll
      for (int m = 0; m < 7; ++m) { lv[m] = lv[m + 1]; li[m] = li[m + 1]; }
      lv[7] = -INFINITY;
      li[7] = 1 << 30;
    }
  }

  int i = ln >> 3, j = ln & 7;
  float v_i = __shfl(wv_cap, i);
  float v_j = __shfl(wv_cap, 32 + j);
  int n_i = __shfl(wn_cap, i);
  int n_j = __shfl(wn_cap, 32 + j);
  float cv = v_i + v_j;
  int ci = n_i * NKEYS + n_j;
  int p = ln;
#pragma unroll
  for (int k = 2; k <= 64; k <<= 1) {
#pragma unroll
    for (int j2 = k >> 1; j2 > 0; j2 >>= 1) {
      float ov = __shfl_xor(cv, j2);
      int op = __shfl_xor(p, j2);
      bool descBlock = ((ln & k) == 0);
      bool lower = ((ln & j2) == 0);
      bool mineBefore = (cv > ov) || (cv == ov && p < op);
      bool keep = (descBlock == lower) ? mineBefore : !mineBefore;
      if (!keep) { cv = ov; p = op; }
    }
  }
  float m0 = __shfl(cv, 0);
  float e = expf(cv - m0);
  float d = e;
#pragma unroll
  for (int off = 1; off < 8; off <<= 1) d += __shfl_xor(d, off);
  int wci = __shfl(ci, p);
  if (ln < TOPK) {
    size_t o = ((size_t)b * NH + h) * TOPK + ln;
    wval[o] = e / d;
    widx[o] = wci;
  }
}

// ---------------- Kernel C: fused gather with in-block compaction (round-10) ----------------
// ONLY change this round: expert-row loads (down + up) are NON-TEMPORAL —
// rows are single-use (chip-wide multiplicity ~2 over 8 XCDs); nt avoids
// polluting L1/L2 with streaming data, preserving x/scores residency.
__global__ __launch_bounds__(1024) void gather_fused(const float* __restrict__ x,
                                                     const float* __restrict__ w_down,
                                                     const float* __restrict__ w_up,
                                                     const int* __restrict__ widx,
                                                     const float* __restrict__ wval,
                                                     float* __restrict__ out) {
  int b = blockIdx.x;
  int tid = threadIdx.x;
  int ln = tid & 63, w = tid >> 6;  // w: 0..15
  __shared__ float part[16][D_MODEL];  // 32 KB
  __shared__ float vals_lds[64];
  __shared__ int   idx_lds[64];
  __shared__ float cval[64];
  __shared__ int   cidx[64];
  __shared__ int   nlive_sh;

  int pbase = b * 64 + w * 4;
  const float4* xr = (const float4*)(x + (size_t)b * D_MODEL);
  float4 x0 = xr[ln * 2], x1 = xr[ln * 2 + 1];

  // ---- phase 1: down dots (4 independent 2KB rows in flight per wave) ----
  int idx0 = widx[pbase + 0];
  int idx1 = widx[pbase + 1];
  int idx2 = widx[pbase + 2];
  int idx3 = widx[pbase + 3];
  const float4* r0 = (const float4*)(w_down + (size_t)idx0 * D_MODEL);
  const float4* r1 = (const float4*)(w_down + (size_t)idx1 * D_MODEL);
  const float4* r2 = (const float4*)(w_down + (size_t)idx2 * D_MODEL);
  const float4* r3 = (const float4*)(w_down + (size_t)idx3 * D_MODEL);
  float4 a0 = ntload(r0 + ln * 2), b0 = ntload(r0 + ln * 2 + 1);
  float4 a1 = ntload(r1 + ln * 2), b1 = ntload(r1 + ln * 2 + 1);
  float4 a2 = ntload(r2 + ln * 2), b2 = ntload(r2 + ln * 2 + 1);
  float4 a3 = ntload(r3 + ln * 2), b3 = ntload(r3 + ln * 2 + 1);

  float d0 = x0.x * a0.x + x0.y * a0.y + x0.z * a0.z + x0.w * a0.w +
             x1.x * b0.x + x1.y * b0.y + x1.z * b0.z + x1.w * b0.w;
  float d1 = x0.x * a1.x + x0.y * a1.y + x0.z * a1.z + x0.w * a1.w +
             x1.x * b1.x + x1.y * b1.y + x1.z * b1.z + x1.w * b1.w;
  float d2 = x0.x * a2.x + x0.y * a2.y + x0.z * a2.z + x0.w * a2.w +
             x1.x * b2.x + x1.y * b2.y + x1.z * b2.z + x1.w * b2.w;
  float d3 = x0.x * a3.x + x0.y * a3.y + x0.z * a3.z + x0.w * a3.w +
             x1.x * b3.x + x1.y * b3.y + x1.z * b3.z + x1.w * b3.w;

#pragma unroll
  for (int off = 32; off; off >>= 1) {
    d0 += __shfl_xor(d0, off);
    d1 += __shfl_xor(d1, off);
    d2 += __shfl_xor(d2, off);
    d3 += __shfl_xor(d3, off);
  }
  if (ln == 0) {
    vals_lds[w * 4 + 0] = fmaxf(d0, 0.f) * wval[pbase + 0];
    vals_lds[w * 4 + 1] = fmaxf(d1, 0.f) * wval[pbase + 1];
    vals_lds[w * 4 + 2] = fmaxf(d2, 0.f) * wval[pbase + 2];
    vals_lds[w * 4 + 3] = fmaxf(d3, 0.f) * wval[pbase + 3];
    idx_lds[w * 4 + 0] = idx0;
    idx_lds[w * 4 + 1] = idx1;
    idx_lds[w * 4 + 2] = idx2;
    idx_lds[w * 4 + 3] = idx3;
  }
  __syncthreads();

  // ---- compaction (wave 0): live pairs -> cval/cidx, stable order ----
  if (w == 0) {
    float v = vals_lds[ln];
    int id = idx_lds[ln];
    bool live = v > 0.f;
    unsigned long long mask = __ballot(live);
    int pos = __popcll(mask & ((1ull << ln) - 1ull));
    if (live) { cval[pos] = v; cidx[pos] = id; }
    if (ln == 0) nlive_sh = (int)__popcll(mask);
  }
  __syncthreads();
  int nlive = nlive_sh;

  // ---- phase 2: streaming up-accumulate over compacted live pairs ----
  float4 ua[4], ub[4];
  float vv[4];
  bool act[4];
#pragma unroll
  for (int r = 0; r < 4; ++r) {
    int p = w + r * 16;
    act[r] = (p < nlive);
    if (act[r]) {
      vv[r] = cval[p];
      const float4* wu = (const float4*)(w_up + (size_t)cidx[p] * D_MODEL);
      ua[r] = ntload(wu + ln * 2);
      ub[r] = ntload(wu + ln * 2 + 1);
    }
  }
  float oa[8];
#pragma unroll
  for (int e = 0; e < 8; ++e) oa[e] = 0.f;
#pragma unroll
  for (int r = 0; r < 4; ++r) {
    if (act[r]) {
      float v = vv[r];
      oa[0] += v * ua[r].x; oa[1] += v * ua[r].y; oa[2] += v * ua[r].z; oa[3] += v * ua[r].w;
      oa[4] += v * ub[r].x; oa[5] += v * ub[r].y; oa[6] += v * ub[r].z; oa[7] += v * ub[r].w;
    }
  }

  *(float4*)&part[w][ln * 8]     = make_float4(oa[0], oa[1], oa[2], oa[3]);
  *(float4*)&part[w][ln * 8 + 4] = make_float4(oa[4], oa[5], oa[6], oa[7]);
  __syncthreads();
  if (tid < D_MODEL) {
    float acc = 0.f;
#pragma unroll
    for (int ww = 0; ww < 16; ++ww) acc += part[ww][tid];
    out[(size_t)b * D_MODEL + tid] = acc;
  }
}

extern "C" void kernel_launch(void* const* d_in, const int* in_sizes, int n_in,
                              void* d_out, int out_size, void* d_ws, size_t ws_size,
                              hipStream_t stream) {
  const float* queries = (const float*)d_in[0];
  const float* Wq      = (const float*)d_in[1];
  const float* bq      = (const float*)d_in[2];
  const float* keys    = (const float*)d_in[3];
  const float* w_down  = (const float*)d_in[4];
  const float* w_up    = (const float*)d_in[5];
  float* outp = (float*)d_out;

  char* base = (char*)d_ws;
  float* qbuf   = (float*)base;                                    // 8 MB
  float* scores = (float*)(base + (size_t)8 * 1024 * 1024);        // 33.5 MB
  int*   widx   = (int*)(base + (size_t)42 * 1024 * 1024);         // 512 KB
  float* wval   = (float*)(base + (size_t)43 * 1024 * 1024);       // 512 KB

  qproj_gemm<<<dim3(16, 32), 256, 0, stream>>>(queries, Wq, bq, qbuf);
  score_gemm<<<dim3(4, 32, 16), 256, 0, stream>>>(qbuf, keys, scores);
  topk_kernel<<<4096, 256, 0, stream>>>(scores, widx, wval);
  gather_fused<<<2048, 1024, 0, stream>>>(queries, w_down, w_up, widx, wval, outp);
}

// Round 13
// 145.323 us; speedup vs baseline: 1.1692x; 1.1692x over previous
//
#include <hip/hip_runtime.h>
#include <math.h>

#define D_MODEL 512
#define NH      8
#define DK      128
#define HALFD   64
#define NKEYS   256
#define TOPK    8
#define NTOK    2048

// ---------------- Kernel A: q = x @ Wq + bq  (fp32 tiled GEMM) ----------------
// M=2048, N=1024, K=512. BM=BN=64, BK=16, 256 threads, 4x4/thread, 512 blocks = 2/CU.
__global__ __launch_bounds__(256) void qproj_gemm(const float* __restrict__ A,
                                                  const float* __restrict__ B,
                                                  const float* __restrict__ bias,
                                                  float* __restrict__ C) {
  const int N = NH * DK, K = D_MODEL;
  __shared__ float As[16][68];
  __shared__ float Bs[16][68];
  int tid = threadIdx.x;
  int tx = tid & 15, ty = tid >> 4;
  int m0 = blockIdx.y * 64, n0 = blockIdx.x * 64;
  int arow = tid >> 2, akk = (tid & 3) << 2;
  int bkr = tid >> 4, bnn = (tid & 15) << 2;
  const float* Aptr = A + (size_t)(m0 + arow) * K + akk;
  const float* Bptr = B + (size_t)bkr * N + n0 + bnn;

  float4 aReg = *(const float4*)Aptr;
  float4 bReg = *(const float4*)Bptr;

  float c[4][4];
#pragma unroll
  for (int i = 0; i < 4; ++i)
#pragma unroll
    for (int j = 0; j < 4; ++j) c[i][j] = 0.f;

  for (int k0 = 0; k0 < K; k0 += 16) {
    As[akk + 0][arow] = aReg.x;
    As[akk + 1][arow] = aReg.y;
    As[akk + 2][arow] = aReg.z;
    As[akk + 3][arow] = aReg.w;
    *(float4*)&Bs[bkr][bnn] = bReg;
    __syncthreads();
    if (k0 + 16 < K) {
      aReg = *(const float4*)(Aptr + k0 + 16);
      bReg = *(const float4*)(Bptr + (size_t)(k0 + 16) * N);
    }
#pragma unroll
    for (int k = 0; k < 16; ++k) {
      float4 a = *(const float4*)&As[k][ty << 2];
      float4 b = *(const float4*)&Bs[k][tx << 2];
      float av[4] = {a.x, a.y, a.z, a.w};
      float bv[4] = {b.x, b.y, b.z, b.w};
#pragma unroll
      for (int i = 0; i < 4; ++i)
#pragma unroll
        for (int j = 0; j < 4; ++j) c[i][j] += av[i] * bv[j];
    }
    __syncthreads();
  }
#pragma unroll
  for (int i = 0; i < 4; ++i) {
    int m = m0 + (ty << 2) + i;
#pragma unroll
    for (int j = 0; j < 4; ++j) {
      int n = n0 + (tx << 2) + j;
      C[(size_t)m * N + n] = c[i][j] + bias[n];
    }
  }
}

// ---------------- Kernel A2: scores = q_half @ keys^T ----------------
__global__ __launch_bounds__(256) void score_gemm(const float* __restrict__ qbuf,
                                                  const float* __restrict__ keys,
                                                  float* __restrict__ scores) {
  __shared__ float As[16][68];
  __shared__ float Bs[16][68];
  int tid = threadIdx.x;
  int tx = tid & 15, ty = tid >> 4;
  int n0 = blockIdx.x * 64, m0 = blockIdx.y * 64, slab = blockIdx.z;
  const float* Ap = qbuf + (size_t)slab * HALFD;
  const float* Bp = keys + (size_t)slab * NKEYS * HALFD;
  float c[4][4];
#pragma unroll
  for (int i = 0; i < 4; ++i)
#pragma unroll
    for (int j = 0; j < 4; ++j) c[i][j] = 0.f;

  for (int k0 = 0; k0 < HALFD; k0 += 16) {
    int row = tid >> 2, kk = (tid & 3) << 2;
    {
      float4 av = *(const float4*)(Ap + (size_t)(m0 + row) * (NH * DK) + k0 + kk);
      As[kk + 0][row] = av.x;
      As[kk + 1][row] = av.y;
      As[kk + 2][row] = av.z;
      As[kk + 3][row] = av.w;
    }
    {
      float4 bv = *(const float4*)(Bp + (size_t)(n0 + row) * HALFD + k0 + kk);
      Bs[kk + 0][row] = bv.x;
      Bs[kk + 1][row] = bv.y;
      Bs[kk + 2][row] = bv.z;
      Bs[kk + 3][row] = bv.w;
    }
    __syncthreads();
#pragma unroll
    for (int k = 0; k < 16; ++k) {
      float4 a = *(const float4*)&As[k][ty << 2];
      float4 b = *(const float4*)&Bs[k][tx << 2];
      float av[4] = {a.x, a.y, a.z, a.w};
      float bv[4] = {b.x, b.y, b.z, b.w};
#pragma unroll
      for (int i = 0; i < 4; ++i)
#pragma unroll
        for (int j = 0; j < 4; ++j) c[i][j] += av[i] * bv[j];
    }
    __syncthreads();
  }
#pragma unroll
  for (int i = 0; i < 4; ++i) {
    int m = m0 + (ty << 2) + i;
    float4 cv = make_float4(c[i][0], c[i][1], c[i][2], c[i][3]);
    *(float4*)&scores[((size_t)m * 16 + slab) * NKEYS + n0 + (tx << 2)] = cv;
  }
}

// ---------------- Kernel B: two-stage top-k + softmax ----------------
#define CE(a, b)                                                        \
  do {                                                                  \
    if (lv[a] < lv[b] || (lv[a] == lv[b] && li[a] > li[b])) {           \
      float tv_ = lv[a]; lv[a] = lv[b]; lv[b] = tv_;                    \
      int ti_ = li[a]; li[a] = li[b]; li[b] = ti_;                      \
    }                                                                   \
  } while (0)

__global__ __launch_bounds__(256) void topk_kernel(const float* __restrict__ scores,
                                                   int* __restrict__ widx,
                                                   float* __restrict__ wval) {
  int tid = threadIdx.x;
  int task = blockIdx.x * 4 + (tid >> 6);
  int ln = tid & 63;
  int b = task >> 3, h = task & 7;
  int s = ln >> 5, l = ln & 31;

  const float* sp = scores + ((size_t)b * 16 + h * 2 + s) * NKEYS + l * 8;
  float lv[8];
  int li[8];
  {
    float4 v0 = *(const float4*)sp;
    float4 v1 = *(const float4*)(sp + 4);
    lv[0] = v0.x; lv[1] = v0.y; lv[2] = v0.z; lv[3] = v0.w;
    lv[4] = v1.x; lv[5] = v1.y; lv[6] = v1.z; lv[7] = v1.w;
#pragma unroll
    for (int m = 0; m < 8; ++m) li[m] = l * 8 + m;
  }
  CE(0, 1); CE(2, 3); CE(0, 2); CE(1, 3); CE(1, 2);
  CE(4, 5); CE(6, 7); CE(4, 6); CE(5, 7); CE(5, 6);
  CE(0, 4); CE(1, 5); CE(2, 6); CE(3, 7);
  CE(2, 4); CE(3, 5);
  CE(1, 2); CE(3, 4); CE(5, 6);

  float wv_cap = 0.f;
  int wn_cap = 0;
#pragma unroll
  for (int k = 0; k < 8; ++k) {
    float v = lv[0];
    int n = li[0];
#pragma unroll
    for (int off = 16; off; off >>= 1) {
      float ov = __shfl_xor(v, off);
      int on = __shfl_xor(n, off);
      if (ov > v || (ov == v && on < n)) { v = ov; n = on; }
    }
    if (l == k) { wv_cap = v; wn_cap = n; }
    if (li[0] == n) {
#pragma unroll
      for (int m = 0; m < 7; ++m) { lv[m] = lv[m + 1]; li[m] = li[m + 1]; }
      lv[7] = -INFINITY;
      li[7] = 1 << 30;
    }
  }

  int i = ln >> 3, j = ln & 7;
  float v_i = __shfl(wv_cap, i);
  float v_j = __shfl(wv_cap, 32 + j);
  int n_i = __shfl(wn_cap, i);
  int n_j = __shfl(wn_cap, 32 + j);
  float cv = v_i + v_j;
  int ci = n_i * NKEYS + n_j;
  int p = ln;
#pragma unroll
  for (int k = 2; k <= 64; k <<= 1) {
#pragma unroll
    for (int j2 = k >> 1; j2 > 0; j2 >>= 1) {
      float ov = __shfl_xor(cv, j2);
      int op = __shfl_xor(p, j2);
      bool descBlock = ((ln & k) == 0);
      bool lower = ((ln & j2) == 0);
      bool mineBefore = (cv > ov) || (cv == ov && p < op);
      bool keep = (descBlock == lower) ? mineBefore : !mineBefore;
      if (!keep) { cv = ov; p = op; }
    }
  }
  float m0 = __shfl(cv, 0);
  float e = expf(cv - m0);
  float d = e;
#pragma unroll
  for (int off = 1; off < 8; off <<= 1) d += __shfl_xor(d, off);
  int wci = __shfl(ci, p);
  if (ln < TOPK) {
    size_t o = ((size_t)b * NH + h) * TOPK + ln;
    wval[o] = e / d;
    widx[o] = wci;
  }
}

// ---------------- Kernel C: fused gather with in-block compaction ----------------
__global__ __launch_bounds__(1024) void gather_fused(const float* __restrict__ x,
                                                     const float* __restrict__ w_down,
                                                     const float* __restrict__ w_up,
                                                     const int* __restrict__ widx,
                                                     const float* __restrict__ wval,
                                                     float* __restrict__ out) {
  int b = blockIdx.x;
  int tid = threadIdx.x;
  int ln = tid & 63, w = tid >> 6;  // w: 0..15
  __shared__ float part[16][D_MODEL];  // 32 KB
  __shared__ float vals_lds[64];
  __shared__ int   idx_lds[64];
  __shared__ float cval[64];
  __shared__ int   cidx[64];
  __shared__ int   nlive_sh;

  int pbase = b * 64 + w * 4;
  const float4* xr = (const float4*)(x + (size_t)b * D_MODEL);
  float4 x0 = xr[ln * 2], x1 = xr[ln * 2 + 1];

  // ---- phase 1: down dots (4 independent 2KB rows in flight per wave) ----
  int idx0 = widx[pbase + 0];
  int idx1 = widx[pbase + 1];
  int idx2 = widx[pbase + 2];
  int idx3 = widx[pbase + 3];
  const float4* r0 = (const float4*)(w_down + (size_t)idx0 * D_MODEL);
  const float4* r1 = (const float4*)(w_down + (size_t)idx1 * D_MODEL);
  const float4* r2 = (const float4*)(w_down + (size_t)idx2 * D_MODEL);
  const float4* r3 = (const float4*)(w_down + (size_t)idx3 * D_MODEL);
  float4 a0 = r0[ln * 2], b0 = r0[ln * 2 + 1];
  float4 a1 = r1[ln * 2], b1 = r1[ln * 2 + 1];
  float4 a2 = r2[ln * 2], b2 = r2[ln * 2 + 1];
  float4 a3 = r3[ln * 2], b3 = r3[ln * 2 + 1];

  float d0 = x0.x * a0.x + x0.y * a0.y + x0.z * a0.z + x0.w * a0.w +
             x1.x * b0.x + x1.y * b0.y + x1.z * b0.z + x1.w * b0.w;
  float d1 = x0.x * a1.x + x0.y * a1.y + x0.z * a1.z + x0.w * a1.w +
             x1.x * b1.x + x1.y * b1.y + x1.z * b1.z + x1.w * b1.w;
  float d2 = x0.x * a2.x + x0.y * a2.y + x0.z * a2.z + x0.w * a2.w +
             x1.x * b2.x + x1.y * b2.y + x1.z * b2.z + x1.w * b2.w;
  float d3 = x0.x * a3.x + x0.y * a3.y + x0.z * a3.z + x0.w * a3.w +
             x1.x * b3.x + x1.y * b3.y + x1.z * b3.z + x1.w * b3.w;

#pragma unroll
  for (int off = 32; off; off >>= 1) {
    d0 += __shfl_xor(d0, off);
    d1 += __shfl_xor(d1, off);
    d2 += __shfl_xor(d2, off);
    d3 += __shfl_xor(d3, off);
  }
  if (ln == 0) {
    vals_lds[w * 4 + 0] = fmaxf(d0, 0.f) * wval[pbase + 0];
    vals_lds[w * 4 + 1] = fmaxf(d1, 0.f) * wval[pbase + 1];
    vals_lds[w * 4 + 2] = fmaxf(d2, 0.f) * wval[pbase + 2];
    vals_lds[w * 4 + 3] = fmaxf(d3, 0.f) * wval[pbase + 3];
    idx_lds[w * 4 + 0] = idx0;
    idx_lds[w * 4 + 1] = idx1;
    idx_lds[w * 4 + 2] = idx2;
    idx_lds[w * 4 + 3] = idx3;
  }
  __syncthreads();

  // ---- compaction (wave 0): live pairs -> cval/cidx, stable order ----
  if (w == 0) {
    float v = vals_lds[ln];
    int id = idx_lds[ln];
    bool live = v > 0.f;
    unsigned long long mask = __ballot(live);
    int pos = __popcll(mask & ((1ull << ln) - 1ull));
    if (live) { cval[pos] = v; cidx[pos] = id; }
    if (ln == 0) nlive_sh = (int)__popcll(mask);
  }
  __syncthreads();
  int nlive = nlive_sh;

  // ---- phase 2: streaming up-accumulate over compacted live pairs ----
  float4 ua[4], ub[4];
  float vv[4];
  bool act[4];
#pragma unroll
  for (int r = 0; r < 4; ++r) {
    int p = w + r * 16;
    act[r] = (p < nlive);
    if (act[r]) {
      vv[r] = cval[p];
      const float4* wu = (const float4*)(w_up + (size_t)cidx[p] * D_MODEL);
      ua[r] = wu[ln * 2];
      ub[r] = wu[ln * 2 + 1];
    }
  }
  float oa[8];
#pragma unroll
  for (int e = 0; e < 8; ++e) oa[e] = 0.f;
#pragma unroll
  for (int r = 0; r < 4; ++r) {
    if (act[r]) {
      float v = vv[r];
      oa[0] += v * ua[r].x; oa[1] += v * ua[r].y; oa[2] += v * ua[r].z; oa[3] += v * ua[r].w;
      oa[4] += v * ub[r].x; oa[5] += v * ub[r].y; oa[6] += v * ub[r].z; oa[7] += v * ub[r].w;
    }
  }

  *(float4*)&part[w][ln * 8]     = make_float4(oa[0], oa[1], oa[2], oa[3]);
  *(float4*)&part[w][ln * 8 + 4] = make_float4(oa[4], oa[5], oa[6], oa[7]);
  __syncthreads();
  if (tid < D_MODEL) {
    float acc = 0.f;
#pragma unroll
    for (int ww = 0; ww < 16; ++ww) acc += part[ww][tid];
    out[(size_t)b * D_MODEL + tid] = acc;
  }
}

extern "C" void kernel_launch(void* const* d_in, const int* in_sizes, int n_in,
                              void* d_out, int out_size, void* d_ws, size_t ws_size,
                              hipStream_t stream) {
  const float* queries = (const float*)d_in[0];
  const float* Wq      = (const float*)d_in[1];
  const float* bq      = (const float*)d_in[2];
  const float* keys    = (const float*)d_in[3];
  const float* w_down  = (const float*)d_in[4];
  const float* w_up    = (const float*)d_in[5];
  float* outp = (float*)d_out;

  char* base = (char*)d_ws;
  float* qbuf   = (float*)base;                                    // 8 MB
  float* scores = (float*)(base + (size_t)8 * 1024 * 1024);        // 33.5 MB
  int*   widx   = (int*)(base + (size_t)42 * 1024 * 1024);         // 512 KB
  float* wval   = (float*)(base + (size_t)43 * 1024 * 1024);       // 512 KB

  qproj_gemm<<<dim3(16, 32), 256, 0, stream>>>(queries, Wq, bq, qbuf);
  score_gemm<<<dim3(4, 32, 16), 256, 0, stream>>>(qbuf, keys, scores);
  topk_kernel<<<4096, 256, 0, stream>>>(scores, widx, wval);
  gather_fused<<<2048, 1024, 0, stream>>>(queries, w_down, w_up, widx, wval, outp);
}